// Round 4
// baseline (26950.116 us; speedup 1.0000x reference)
//
#include <hip/hip_runtime.h>
#include <hip/hip_cooperative_groups.h>
#include <math.h>

namespace cg = cooperative_groups;

// Problem constants
#define SS 256   // encoder seq len
#define BB 256   // batch
#define HH 512   // hidden
#define OO 64    // output dim
#define NSTEP 63 // only outs[:63] are used

// ---------------------------------------------------------------------------
// K0: EW = enc @ Wa_bot  (M=65536, K=512, N=512), fp32, 128x128 tile.
// Output relayout: row m = s*256+b  ->  EW[b][s][h]  (contiguous per batch b)
// ---------------------------------------------------------------------------
__global__ __launch_bounds__(256) void k_ew_gemm(const float* __restrict__ A,
                                                 const float* __restrict__ Bm,
                                                 float* __restrict__ C)
{
    __shared__ float As[8][132];
    __shared__ float Bs[8][132];
    const int tid = threadIdx.x;
    const int bm = blockIdx.x * 128;
    const int bn = blockIdx.y * 128;
    const int tx = tid & 15;
    const int ty = tid >> 4;
    const int a_row = tid >> 1;
    const int a_k4 = (tid & 1) * 4;
    const int b_row = tid >> 5;
    const int b_n4 = (tid & 31) * 4;

    float acc[8][8];
#pragma unroll
    for (int i = 0; i < 8; i++)
#pragma unroll
        for (int j = 0; j < 8; j++) acc[i][j] = 0.f;

    for (int kt = 0; kt < 512; kt += 8) {
        float4 av = *(const float4*)(A + (size_t)(bm + a_row) * 512 + kt + a_k4);
        As[a_k4 + 0][a_row] = av.x;
        As[a_k4 + 1][a_row] = av.y;
        As[a_k4 + 2][a_row] = av.z;
        As[a_k4 + 3][a_row] = av.w;
        *(float4*)(&Bs[b_row][b_n4]) = *(const float4*)(Bm + (size_t)(kt + b_row) * 512 + bn + b_n4);
        __syncthreads();
#pragma unroll
        for (int kk = 0; kk < 8; kk++) {
            float av8[8], bv8[8];
            *(float4*)&av8[0] = *(const float4*)&As[kk][ty * 4];
            *(float4*)&av8[4] = *(const float4*)&As[kk][64 + ty * 4];
            *(float4*)&bv8[0] = *(const float4*)&Bs[kk][tx * 4];
            *(float4*)&bv8[4] = *(const float4*)&Bs[kk][64 + tx * 4];
#pragma unroll
            for (int i = 0; i < 8; i++)
#pragma unroll
                for (int j = 0; j < 8; j++) acc[i][j] += av8[i] * bv8[j];
        }
        __syncthreads();
    }
#pragma unroll
    for (int i = 0; i < 8; i++) {
        int m = bm + ((i < 4) ? (ty * 4 + i) : (64 + ty * 4 + i - 4));
        int mrow = (m & 255) * 256 + (m >> 8);   // [b][s] relayout
        float4 o0 = make_float4(acc[i][0], acc[i][1], acc[i][2], acc[i][3]);
        float4 o1 = make_float4(acc[i][4], acc[i][5], acc[i][6], acc[i][7]);
        *(float4*)(C + (size_t)mrow * 512 + bn + tx * 4) = o0;
        *(float4*)(C + (size_t)mrow * 512 + bn + 64 + tx * 4) = o1;
    }
}

// ---------------------------------------------------------------------------
// q init: qpre = h0 @ Wa_top   (no bias; ba added in the attention phase)
// ---------------------------------------------------------------------------
__global__ __launch_bounds__(256) void k_qinit(const float* __restrict__ A,
                                               const float* __restrict__ Wa,
                                               float* __restrict__ qpre)
{
    __shared__ float As[32][33];
    __shared__ float Bs[32][33];
    const int tid = threadIdx.x;
    const int bn = blockIdx.x * 32;
    const int bm = blockIdx.y * 32;
    const int tx = tid & 15;
    const int ty = tid >> 4;
    const int l_row = tid >> 3;
    const int l_c4 = (tid & 7) * 4;

    float acc00 = 0.f, acc01 = 0.f, acc10 = 0.f, acc11 = 0.f;
    for (int kt = 0; kt < 512; kt += 32) {
#pragma unroll
        for (int i = 0; i < 4; i++)
            As[l_c4 + i][l_row] = A[(size_t)(bm + l_row) * 512 + kt + l_c4 + i];
#pragma unroll
        for (int i = 0; i < 4; i++)
            Bs[l_row][l_c4 + i] = Wa[(size_t)(kt + l_row) * 512 + bn + l_c4 + i];
        __syncthreads();
#pragma unroll
        for (int kk = 0; kk < 32; kk++) {
            float a0 = As[kk][ty * 2], a1 = As[kk][ty * 2 + 1];
            float b0 = Bs[kk][tx * 2], b1 = Bs[kk][tx * 2 + 1];
            acc00 += a0 * b0; acc01 += a0 * b1;
            acc10 += a1 * b0; acc11 += a1 * b1;
        }
        __syncthreads();
    }
    qpre[(size_t)(bm + ty * 2) * 512 + bn + tx * 2]     = acc00;
    qpre[(size_t)(bm + ty * 2) * 512 + bn + tx * 2 + 1] = acc01;
    qpre[(size_t)(bm + ty * 2 + 1) * 512 + bn + tx * 2]     = acc10;
    qpre[(size_t)(bm + ty * 2 + 1) * 512 + bn + tx * 2 + 1] = acc11;
}

// ---------------------------------------------------------------------------
// Persistent cooperative decode kernel: 256 blocks x 512 threads.
// Per step: Phase A (attention, block=b) -> grid.sync ->
//           Phase BCD (blocks 0..63: 4 m-rows each: h-GEMM, out+q GEMM,
//           argmax, one-hot, dout store; h/x state LDS-resident) -> grid.sync
// ---------------------------------------------------------------------------
__global__ __launch_bounds__(512, 1) void k_decode(
    const float* __restrict__ EW, const float* __restrict__ enc,
    const float* __restrict__ sos, const float* __restrict__ h0,
    const float* __restrict__ Wa,
    const float* __restrict__ ba, const float* __restrict__ vvec,
    const float* __restrict__ W_ih, const float* __restrict__ b_ih,
    const float* __restrict__ W_hh, const float* __restrict__ b_hh,
    const float* __restrict__ Wo, const float* __restrict__ bo,
    float* __restrict__ qpre, float* __restrict__ ctx,
    float* __restrict__ dout)
{
    cg::grid_group grid = cg::this_grid();
    const int bid = blockIdx.x;
    const int tid = threadIdx.x;

    // persistent decoder state (blocks 0..63 only): rows m0..m0+3
    __shared__ float hrow[4][HH];     // 8 KB
    __shared__ float xrow[4][OO];     // 1 KB
    // BCD staging (dead during phase A)
    __shared__ float arow[4][1088];   // 17.4 KB
    // phase A scratch
    __shared__ float qs[512], vs[512], sc[256], red[16];

    const int m0 = bid * 4;
    if (bid < 64) {
#pragma unroll
        for (int r = 0; r < 4; r++) {
            if (tid < HH) hrow[r][tid] = h0[(m0 + r) * HH + tid];
            if (tid < OO) xrow[r][tid] = sos[(m0 + r) * OO + tid];
        }
    }
    // first reads of hrow/xrow happen after phase A's __syncthreads + grid.sync

    for (int t = 0; t < NSTEP; t++) {
        // ================= Phase A: attention for b = bid =================
        {
            const int b = bid;
            qs[tid] = qpre[b * HH + tid] + ba[tid];
            vs[tid] = vvec[tid];
            __syncthreads();

            const int w = tid >> 6;
            const int l = tid & 63;
            const float* qp0 = qs + l * 4;
            const float* vp0 = vs + l * 4;
            const float* qp1 = qs + 256 + l * 4;
            const float* vp1 = vs + 256 + l * 4;

            for (int i = 0; i < 32; i++) {
                int s = w * 32 + i;
                const float4* p4 = (const float4*)(EW + ((size_t)(b * 256 + s)) * 512);
                float4 e0 = p4[l];
                float4 e1 = p4[l + 64];
                float a;
                a  = vp0[0] * tanhf(e0.x + qp0[0]);
                a += vp0[1] * tanhf(e0.y + qp0[1]);
                a += vp0[2] * tanhf(e0.z + qp0[2]);
                a += vp0[3] * tanhf(e0.w + qp0[3]);
                a += vp1[0] * tanhf(e1.x + qp1[0]);
                a += vp1[1] * tanhf(e1.y + qp1[1]);
                a += vp1[2] * tanhf(e1.z + qp1[2]);
                a += vp1[3] * tanhf(e1.w + qp1[3]);
#pragma unroll
                for (int off = 32; off; off >>= 1) a += __shfl_down(a, off);
                if (l == 0) sc[s] = a;
            }
            __syncthreads();

            if (tid < 256) {
                float m = sc[tid];
#pragma unroll
                for (int off = 32; off; off >>= 1) m = fmaxf(m, __shfl_down(m, off));
                if ((tid & 63) == 0) red[tid >> 6] = m;
            }
            __syncthreads();
            if (tid < 256) {
                float mx = fmaxf(fmaxf(red[0], red[1]), fmaxf(red[2], red[3]));
                float e = expf(sc[tid] - mx);
                sc[tid] = e;
                float ssum = e;
#pragma unroll
                for (int off = 32; off; off >>= 1) ssum += __shfl_down(ssum, off);
                if ((tid & 63) == 0) red[8 + (tid >> 6)] = ssum;
            }
            __syncthreads();
            const float inv = 1.0f / (red[8] + red[9] + red[10] + red[11]);

            const float* ep = enc + b * 512 + tid;
            float acc = 0.f;
#pragma unroll 4
            for (int s = 0; s < 256; s++) {
                acc += sc[s] * ep[(size_t)s * (256 * 512)];
            }
            ctx[b * 512 + tid] = acc * inv;
        }
        grid.sync();

        // ========== Phase BCD: blocks 0..63, rows m0..m0+3 ==========
        if (bid < 64) {
            // assemble arow = [x | ctx | h]  (k: 0..63 | 64..575 | 576..1087)
#pragma unroll
            for (int r = 0; r < 4; r++) {
                if (tid < 64) arow[r][tid] = xrow[r][tid];
                arow[r][64 + tid]  = ctx[(m0 + r) * HH + tid];
                arow[r][576 + tid] = hrow[r][tid];
            }
            __syncthreads();

            // ---- hnew: thread -> (m = tid>>7, 4 consecutive n) ----
            {
                const int m = tid >> 7;
                const int n0 = (tid & 127) * 4;
                const float* wi0 = W_ih + (size_t)(n0 + 0) * 576;
                const float* wi1 = W_ih + (size_t)(n0 + 1) * 576;
                const float* wi2 = W_ih + (size_t)(n0 + 2) * 576;
                const float* wi3 = W_ih + (size_t)(n0 + 3) * 576;
                float a0 = 0.f, a1 = 0.f, a2 = 0.f, a3 = 0.f;
#pragma unroll 4
                for (int k = 0; k < 576; k += 4) {
                    float4 a4 = *(const float4*)&arow[m][k];
                    float4 w;
                    w = *(const float4*)(wi0 + k); a0 += a4.x*w.x + a4.y*w.y + a4.z*w.z + a4.w*w.w;
                    w = *(const float4*)(wi1 + k); a1 += a4.x*w.x + a4.y*w.y + a4.z*w.z + a4.w*w.w;
                    w = *(const float4*)(wi2 + k); a2 += a4.x*w.x + a4.y*w.y + a4.z*w.z + a4.w*w.w;
                    w = *(const float4*)(wi3 + k); a3 += a4.x*w.x + a4.y*w.y + a4.z*w.z + a4.w*w.w;
                }
                const float* wh0 = W_hh + (size_t)(n0 + 0) * 512;
                const float* wh1 = W_hh + (size_t)(n0 + 1) * 512;
                const float* wh2 = W_hh + (size_t)(n0 + 2) * 512;
                const float* wh3 = W_hh + (size_t)(n0 + 3) * 512;
#pragma unroll 4
                for (int k = 0; k < 512; k += 4) {
                    float4 a4 = *(const float4*)&arow[m][576 + k];
                    float4 w;
                    w = *(const float4*)(wh0 + k); a0 += a4.x*w.x + a4.y*w.y + a4.z*w.z + a4.w*w.w;
                    w = *(const float4*)(wh1 + k); a1 += a4.x*w.x + a4.y*w.y + a4.z*w.z + a4.w*w.w;
                    w = *(const float4*)(wh2 + k); a2 += a4.x*w.x + a4.y*w.y + a4.z*w.z + a4.w*w.w;
                    w = *(const float4*)(wh3 + k); a3 += a4.x*w.x + a4.y*w.y + a4.z*w.z + a4.w*w.w;
                }
                float4 hv;
                hv.x = tanhf(a0 + b_ih[n0 + 0] + b_hh[n0 + 0]);
                hv.y = tanhf(a1 + b_ih[n0 + 1] + b_hh[n0 + 1]);
                hv.z = tanhf(a2 + b_ih[n0 + 2] + b_hh[n0 + 2]);
                hv.w = tanhf(a3 + b_ih[n0 + 3] + b_hh[n0 + 3]);
                *(float4*)&hrow[m][n0] = hv;   // arow holds old h; safe
            }
            __syncthreads();

            // ---- qnext = hnew @ Wa_top : thread -> (m, 4 consecutive n) ----
            {
                const int m = tid >> 7;
                const int n0 = (tid & 127) * 4;
                float qx = 0.f, qy = 0.f, qz = 0.f, qw = 0.f;
#pragma unroll 4
                for (int k = 0; k < 512; k += 4) {
                    float4 a4 = *(const float4*)&hrow[m][k];
                    float4 w;
                    w = *(const float4*)(Wa + (size_t)(k + 0) * 512 + n0);
                    qx += a4.x * w.x; qy += a4.x * w.y; qz += a4.x * w.z; qw += a4.x * w.w;
                    w = *(const float4*)(Wa + (size_t)(k + 1) * 512 + n0);
                    qx += a4.y * w.x; qy += a4.y * w.y; qz += a4.y * w.z; qw += a4.y * w.w;
                    w = *(const float4*)(Wa + (size_t)(k + 2) * 512 + n0);
                    qx += a4.z * w.x; qy += a4.z * w.y; qz += a4.z * w.z; qw += a4.z * w.w;
                    w = *(const float4*)(Wa + (size_t)(k + 3) * 512 + n0);
                    qx += a4.w * w.x; qy += a4.w * w.y; qz += a4.w * w.z; qw += a4.w * w.w;
                }
                float4 qv = make_float4(qx, qy, qz, qw);
                *(float4*)(qpre + (size_t)(m0 + m) * 512 + n0) = qv;
            }

            // ---- out = hnew @ Wo^T + bo ; dout store; argmax -> one-hot ----
            if (tid < 256) {
                const int m = tid >> 6;   // wave index == m
                const int n = tid & 63;
                const float* wo = Wo + (size_t)n * 512;
                float acc = 0.f;
#pragma unroll 4
                for (int k = 0; k < 512; k += 4) {
                    float4 a4 = *(const float4*)&hrow[m][k];
                    float4 w4 = *(const float4*)(wo + k);
                    acc += a4.x * w4.x + a4.y * w4.y + a4.z * w4.z + a4.w * w4.w;
                }
                float ov = acc + bo[n];
                dout[(size_t)(m0 + m) * (OO * NSTEP) + n * NSTEP + t] = ov;
                float bv = ov;
                int bi = n;
#pragma unroll
                for (int off = 1; off < 64; off <<= 1) {
                    float o_v = __shfl_xor(bv, off);
                    int   o_i = __shfl_xor(bi, off);
                    if (o_v > bv || (o_v == bv && o_i < bi)) { bv = o_v; bi = o_i; }
                }
                xrow[m][n] = (n == bi) ? 1.0f : 0.0f;
            }
            // xrow/hrow next read after grid.sync (full barrier) — safe
        }
        grid.sync();
    }
}

// ---------------------------------------------------------------------------
extern "C" void kernel_launch(void* const* d_in, const int* in_sizes, int n_in,
                              void* d_out, int out_size, void* d_ws, size_t ws_size,
                              hipStream_t stream)
{
    const float* sos  = (const float*)d_in[0];
    const float* h0   = (const float*)d_in[1];
    const float* enc  = (const float*)d_in[2];
    const float* Wa   = (const float*)d_in[3];
    const float* ba   = (const float*)d_in[4];
    const float* vvec = (const float*)d_in[5];
    const float* W_ih = (const float*)d_in[6];
    const float* b_ih = (const float*)d_in[7];
    const float* W_hh = (const float*)d_in[8];
    const float* b_hh = (const float*)d_in[9];
    const float* Wo   = (const float*)d_in[10];
    const float* bo   = (const float*)d_in[11];
    float* out = (float*)d_out;

    // Workspace: 33,816,576 floats (135.3 MB) — under the verified budget.
    float* ws = (float*)d_ws;
    float* EW   = ws; ws += (size_t)SS * BB * HH;   // 33,554,432  [b][s][h]
    float* qpre = ws; ws += BB * HH;
    float* ctxb = ws; ws += BB * HH;

    // ---- Precompute ----
    k_ew_gemm<<<dim3(512, 4), 256, 0, stream>>>(enc, Wa + 512 * 512, EW);
    k_qinit<<<dim3(16, 8), 256, 0, stream>>>(h0, Wa, qpre);

    // ---- Whole decode loop: one cooperative launch ----
    void* args[] = {
        (void*)&EW, (void*)&enc, (void*)&sos, (void*)&h0,
        (void*)&Wa, (void*)&ba, (void*)&vvec,
        (void*)&W_ih, (void*)&b_ih, (void*)&W_hh, (void*)&b_hh,
        (void*)&Wo, (void*)&bo,
        (void*)&qpre, (void*)&ctxb, (void*)&out
    };
    hipLaunchCooperativeKernel((void*)k_decode, dim3(256), dim3(512),
                               args, 0, stream);
}

// Round 5
// 12628.308 us; speedup vs baseline: 2.1341x; 2.1341x over previous
//
#include <hip/hip_runtime.h>
#include <math.h>

// Problem constants
#define SS 256   // encoder seq len
#define BB 256   // batch
#define HH 512   // hidden
#define OO 64    // output dim
#define NSTEP 63 // only outs[:63] are used

// ---------------------------------------------------------------------------
// K0: EW = enc @ Wa_bot  (M=65536, K=512, N=512), fp32, 128x128 tile.
// Output relayout: row m = s*256+b  ->  EW[b][s][h]  (contiguous per batch b)
// ---------------------------------------------------------------------------
__global__ __launch_bounds__(256) void k_ew_gemm(const float* __restrict__ A,
                                                 const float* __restrict__ Bm,
                                                 float* __restrict__ C)
{
    __shared__ float As[8][132];
    __shared__ float Bs[8][132];
    const int tid = threadIdx.x;
    const int bm = blockIdx.x * 128;
    const int bn = blockIdx.y * 128;
    const int tx = tid & 15;
    const int ty = tid >> 4;
    const int a_row = tid >> 1;
    const int a_k4 = (tid & 1) * 4;
    const int b_row = tid >> 5;
    const int b_n4 = (tid & 31) * 4;

    float acc[8][8];
#pragma unroll
    for (int i = 0; i < 8; i++)
#pragma unroll
        for (int j = 0; j < 8; j++) acc[i][j] = 0.f;

    for (int kt = 0; kt < 512; kt += 8) {
        float4 av = *(const float4*)(A + (size_t)(bm + a_row) * 512 + kt + a_k4);
        As[a_k4 + 0][a_row] = av.x;
        As[a_k4 + 1][a_row] = av.y;
        As[a_k4 + 2][a_row] = av.z;
        As[a_k4 + 3][a_row] = av.w;
        *(float4*)(&Bs[b_row][b_n4]) = *(const float4*)(Bm + (size_t)(kt + b_row) * 512 + bn + b_n4);
        __syncthreads();
#pragma unroll
        for (int kk = 0; kk < 8; kk++) {
            float av8[8], bv8[8];
            *(float4*)&av8[0] = *(const float4*)&As[kk][ty * 4];
            *(float4*)&av8[4] = *(const float4*)&As[kk][64 + ty * 4];
            *(float4*)&bv8[0] = *(const float4*)&Bs[kk][tx * 4];
            *(float4*)&bv8[4] = *(const float4*)&Bs[kk][64 + tx * 4];
#pragma unroll
            for (int i = 0; i < 8; i++)
#pragma unroll
                for (int j = 0; j < 8; j++) acc[i][j] += av8[i] * bv8[j];
        }
        __syncthreads();
    }
#pragma unroll
    for (int i = 0; i < 8; i++) {
        int m = bm + ((i < 4) ? (ty * 4 + i) : (64 + ty * 4 + i - 4));
        int mrow = (m & 255) * 256 + (m >> 8);   // [b][s] relayout
        float4 o0 = make_float4(acc[i][0], acc[i][1], acc[i][2], acc[i][3]);
        float4 o1 = make_float4(acc[i][4], acc[i][5], acc[i][6], acc[i][7]);
        *(float4*)(C + (size_t)mrow * 512 + bn + tx * 4) = o0;
        *(float4*)(C + (size_t)mrow * 512 + bn + 64 + tx * 4) = o1;
    }
}

// ---------------------------------------------------------------------------
// q init: qpre = h0 @ Wa_top   (no bias; ba added in the attention phase)
// ---------------------------------------------------------------------------
__global__ __launch_bounds__(256) void k_qinit(const float* __restrict__ A,
                                               const float* __restrict__ Wa,
                                               float* __restrict__ qpre)
{
    __shared__ float As[32][33];
    __shared__ float Bs[32][33];
    const int tid = threadIdx.x;
    const int bn = blockIdx.x * 32;
    const int bm = blockIdx.y * 32;
    const int tx = tid & 15;
    const int ty = tid >> 4;
    const int l_row = tid >> 3;
    const int l_c4 = (tid & 7) * 4;

    float acc00 = 0.f, acc01 = 0.f, acc10 = 0.f, acc11 = 0.f;
    for (int kt = 0; kt < 512; kt += 32) {
#pragma unroll
        for (int i = 0; i < 4; i++)
            As[l_c4 + i][l_row] = A[(size_t)(bm + l_row) * 512 + kt + l_c4 + i];
#pragma unroll
        for (int i = 0; i < 4; i++)
            Bs[l_row][l_c4 + i] = Wa[(size_t)(kt + l_row) * 512 + bn + l_c4 + i];
        __syncthreads();
#pragma unroll
        for (int kk = 0; kk < 32; kk++) {
            float a0 = As[kk][ty * 2], a1 = As[kk][ty * 2 + 1];
            float b0 = Bs[kk][tx * 2], b1 = Bs[kk][tx * 2 + 1];
            acc00 += a0 * b0; acc01 += a0 * b1;
            acc10 += a1 * b0; acc11 += a1 * b1;
        }
        __syncthreads();
    }
    qpre[(size_t)(bm + ty * 2) * 512 + bn + tx * 2]     = acc00;
    qpre[(size_t)(bm + ty * 2) * 512 + bn + tx * 2 + 1] = acc01;
    qpre[(size_t)(bm + ty * 2 + 1) * 512 + bn + tx * 2]     = acc10;
    qpre[(size_t)(bm + ty * 2 + 1) * 512 + bn + tx * 2 + 1] = acc11;
}

// WoT[k][n] = Wo[n][k]  (512 x 64), one-time tiny transpose
__global__ __launch_bounds__(256) void k_wot(const float* __restrict__ Wo,
                                             float* __restrict__ WoT)
{
    int idx = blockIdx.x * 256 + threadIdx.x;   // 0..32767
    int k = idx >> 6, n = idx & 63;
    WoT[idx] = Wo[n * 512 + k];
}

// ---------------------------------------------------------------------------
// k_attn2: attention for batch b = blockIdx.x. 1024 threads (16 waves).
// score[s] = v . tanh(EW[b][s][:] + q[b][:]); attn = softmax_s; ctx = attn@enc
// EW layout [b][s][h] -> each block streams 512 KB contiguously.
// ---------------------------------------------------------------------------
__global__ __launch_bounds__(1024) void k_attn2(const float* __restrict__ EW,
                                                const float* __restrict__ enc,
                                                const float* __restrict__ qpre,
                                                const float* __restrict__ ba,
                                                const float* __restrict__ vvec,
                                                float* __restrict__ ctx)
{
    __shared__ float qs[512];
    __shared__ float vs[512];
    __shared__ float sc[256];
    __shared__ float red[16];
    __shared__ float partl[512];
    const int b = blockIdx.x;
    const int tid = threadIdx.x;

    if (tid < 512) {
        qs[tid] = qpre[b * 512 + tid] + ba[tid];
        vs[tid] = vvec[tid];
    }
    __syncthreads();

    const int w = tid >> 6;     // wave 0..15
    const int l = tid & 63;
    const float* qp0 = qs + l * 4;
    const float* vp0 = vs + l * 4;
    const float* qp1 = qs + 256 + l * 4;
    const float* vp1 = vs + 256 + l * 4;

    // 16 s-values per wave
    for (int i = 0; i < 16; i++) {
        int s = w * 16 + i;
        const float4* p4 = (const float4*)(EW + ((size_t)(b * 256 + s)) * 512);
        float4 e0 = p4[l];
        float4 e1 = p4[l + 64];
        float a;
        a  = vp0[0] * tanhf(e0.x + qp0[0]);
        a += vp0[1] * tanhf(e0.y + qp0[1]);
        a += vp0[2] * tanhf(e0.z + qp0[2]);
        a += vp0[3] * tanhf(e0.w + qp0[3]);
        a += vp1[0] * tanhf(e1.x + qp1[0]);
        a += vp1[1] * tanhf(e1.y + qp1[1]);
        a += vp1[2] * tanhf(e1.z + qp1[2]);
        a += vp1[3] * tanhf(e1.w + qp1[3]);
#pragma unroll
        for (int off = 32; off; off >>= 1) a += __shfl_down(a, off);
        if (l == 0) sc[s] = a;
    }
    __syncthreads();

    if (tid < 256) {
        float m = sc[tid];
#pragma unroll
        for (int off = 32; off; off >>= 1) m = fmaxf(m, __shfl_down(m, off));
        if ((tid & 63) == 0) red[tid >> 6] = m;
    }
    __syncthreads();
    if (tid < 256) {
        float mx = fmaxf(fmaxf(red[0], red[1]), fmaxf(red[2], red[3]));
        float e = expf(sc[tid] - mx);
        sc[tid] = e;
        float ssum = e;
#pragma unroll
        for (int off = 32; off; off >>= 1) ssum += __shfl_down(ssum, off);
        if ((tid & 63) == 0) red[8 + (tid >> 6)] = ssum;
    }
    __syncthreads();
    const float inv = 1.0f / (red[8] + red[9] + red[10] + red[11]);

    // context: h = tid&511, s-half = tid>>9; two partials, LDS combine
    const int h = tid & 511;
    const int half = tid >> 9;
    const float* ep = enc + b * 512 + h;
    float acc = 0.f;
    const int s0 = half * 128;
#pragma unroll 4
    for (int s = s0; s < s0 + 128; s++) {
        acc += sc[s] * ep[(size_t)s * (256 * 512)];
    }
    if (half == 1) partl[h] = acc;
    __syncthreads();
    if (half == 0) ctx[b * 512 + h] = (acc + partl[h]) * inv;
}

// ---------------------------------------------------------------------------
// k_bcd: 64 blocks x 512 threads; block handles batch rows m0..m0+3.
// Fused: h_new (K=1088), q_next = h@Wa_top, out = h@Wo^T + bo, dout store,
// argmax -> one-hot x.  State (h, x) in global (hst, xst).
// Thread owns ONE n-column -> weights read once/block; activations are LDS
// broadcasts (all lanes read the same address -> conflict-free).
// ---------------------------------------------------------------------------
__global__ __launch_bounds__(512) void k_bcd(
    const float* __restrict__ xin,   // [256][64]  (sos at t=0, else xst)
    const float* __restrict__ hin,   // [256][512] (h0 at t=0, else hst)
    const float* __restrict__ ctx,
    const float* __restrict__ Wa,
    const float* __restrict__ W_ih, const float* __restrict__ b_ih,
    const float* __restrict__ W_hh, const float* __restrict__ b_hh,
    const float* __restrict__ WoT, const float* __restrict__ bo,
    float* __restrict__ qpre, float* __restrict__ hst,
    float* __restrict__ xst, float* __restrict__ dout, int t)
{
    __shared__ float arow[4][1088];   // [x | ctx | h_prev]
    __shared__ float hnew[4][512];
    const int bid = blockIdx.x;
    const int tid = threadIdx.x;
    const int m0 = bid * 4;

#pragma unroll
    for (int r = 0; r < 4; r++) {
        if (tid < 64) arow[r][tid] = xin[(m0 + r) * 64 + tid];
        arow[r][64 + tid]  = ctx[(m0 + r) * 512 + tid];
        arow[r][576 + tid] = hin[(m0 + r) * 512 + tid];
    }
    __syncthreads();

    // ---- h-GEMM: thread -> n=tid; 4 m-accumulators ----
    {
        const int n = tid;
        float a0 = 0.f, a1 = 0.f, a2 = 0.f, a3 = 0.f;
        const float* wi = W_ih + (size_t)n * 576;
#pragma unroll 4
        for (int k = 0; k < 576; k += 4) {
            float4 w4 = *(const float4*)(wi + k);
            float4 v0 = *(const float4*)&arow[0][k];
            float4 v1 = *(const float4*)&arow[1][k];
            float4 v2 = *(const float4*)&arow[2][k];
            float4 v3 = *(const float4*)&arow[3][k];
            a0 += v0.x*w4.x + v0.y*w4.y + v0.z*w4.z + v0.w*w4.w;
            a1 += v1.x*w4.x + v1.y*w4.y + v1.z*w4.z + v1.w*w4.w;
            a2 += v2.x*w4.x + v2.y*w4.y + v2.z*w4.z + v2.w*w4.w;
            a3 += v3.x*w4.x + v3.y*w4.y + v3.z*w4.z + v3.w*w4.w;
        }
        const float* wh = W_hh + (size_t)n * 512;
#pragma unroll 4
        for (int k = 0; k < 512; k += 4) {
            float4 w4 = *(const float4*)(wh + k);
            float4 v0 = *(const float4*)&arow[0][576 + k];
            float4 v1 = *(const float4*)&arow[1][576 + k];
            float4 v2 = *(const float4*)&arow[2][576 + k];
            float4 v3 = *(const float4*)&arow[3][576 + k];
            a0 += v0.x*w4.x + v0.y*w4.y + v0.z*w4.z + v0.w*w4.w;
            a1 += v1.x*w4.x + v1.y*w4.y + v1.z*w4.z + v1.w*w4.w;
            a2 += v2.x*w4.x + v2.y*w4.y + v2.z*w4.z + v2.w*w4.w;
            a3 += v3.x*w4.x + v3.y*w4.y + v3.z*w4.z + v3.w*w4.w;
        }
        const float bb = b_ih[n] + b_hh[n];
        float h0v = tanhf(a0 + bb), h1v = tanhf(a1 + bb);
        float h2v = tanhf(a2 + bb), h3v = tanhf(a3 + bb);
        hnew[0][n] = h0v; hst[(size_t)(m0 + 0) * 512 + n] = h0v;
        hnew[1][n] = h1v; hst[(size_t)(m0 + 1) * 512 + n] = h1v;
        hnew[2][n] = h2v; hst[(size_t)(m0 + 2) * 512 + n] = h2v;
        hnew[3][n] = h3v; hst[(size_t)(m0 + 3) * 512 + n] = h3v;
    }
    __syncthreads();

    // ---- q-GEMM: q[m][n] = sum_k hnew[m][k] * Wa[k][n]  (coalesced Wa) ----
    {
        const int n = tid;
        float q0 = 0.f, q1 = 0.f, q2 = 0.f, q3 = 0.f;
#pragma unroll 4
        for (int k = 0; k < 512; k++) {
            float wv = Wa[(size_t)k * 512 + n];
            q0 += hnew[0][k] * wv;
            q1 += hnew[1][k] * wv;
            q2 += hnew[2][k] * wv;
            q3 += hnew[3][k] * wv;
        }
        qpre[(size_t)(m0 + 0) * 512 + n] = q0;
        qpre[(size_t)(m0 + 1) * 512 + n] = q1;
        qpre[(size_t)(m0 + 2) * 512 + n] = q2;
        qpre[(size_t)(m0 + 3) * 512 + n] = q3;
    }

    // ---- out-GEMM + argmax (waves 0..3: m = wave, n = lane) ----
    if (tid < 256) {
        const int m = tid >> 6;
        const int n = tid & 63;
        float acc = 0.f;
#pragma unroll 4
        for (int k = 0; k < 512; k++) {
            acc += hnew[m][k] * WoT[k * 64 + n];   // coalesced across lanes
        }
        float ov = acc + bo[n];
        dout[(size_t)(m0 + m) * (OO * NSTEP) + n * NSTEP + t] = ov;
        float bv = ov;
        int bi = n;
#pragma unroll
        for (int off = 1; off < 64; off <<= 1) {
            float o_v = __shfl_xor(bv, off);
            int   o_i = __shfl_xor(bi, off);
            if (o_v > bv || (o_v == bv && o_i < bi)) { bv = o_v; bi = o_i; }
        }
        xst[(m0 + m) * 64 + n] = (n == bi) ? 1.0f : 0.0f;
    }
}

// ---------------------------------------------------------------------------
extern "C" void kernel_launch(void* const* d_in, const int* in_sizes, int n_in,
                              void* d_out, int out_size, void* d_ws, size_t ws_size,
                              hipStream_t stream)
{
    const float* sos  = (const float*)d_in[0];
    const float* h0   = (const float*)d_in[1];
    const float* enc  = (const float*)d_in[2];
    const float* Wa   = (const float*)d_in[3];
    const float* ba   = (const float*)d_in[4];
    const float* vvec = (const float*)d_in[5];
    const float* W_ih = (const float*)d_in[6];
    const float* b_ih = (const float*)d_in[7];
    const float* W_hh = (const float*)d_in[8];
    const float* b_hh = (const float*)d_in[9];
    const float* Wo   = (const float*)d_in[10];
    const float* bo   = (const float*)d_in[11];
    float* out = (float*)d_out;

    // Workspace: 33,996,800 floats (136.0 MB) <= verified budget 34,111,488.
    float* ws = (float*)d_ws;
    float* EW   = ws; ws += (size_t)SS * BB * HH;   // 33,554,432  [b][s][h]
    float* qpre = ws; ws += BB * HH;                // 131,072
    float* ctxb = ws; ws += BB * HH;                // 131,072
    float* hst  = ws; ws += BB * HH;                // 131,072
    float* xst  = ws; ws += BB * OO;                // 16,384
    float* WoT  = ws; ws += HH * OO;                // 32,768

    // ---- Precompute ----
    k_ew_gemm<<<dim3(512, 4), 256, 0, stream>>>(enc, Wa + 512 * 512, EW);
    k_qinit<<<dim3(16, 8), 256, 0, stream>>>(h0, Wa, qpre);
    k_wot<<<128, 256, 0, stream>>>(Wo, WoT);

    // ---- 63 decode steps: 2 kernels per step ----
    for (int t = 0; t < NSTEP; t++) {
        const float* xin = (t == 0) ? sos : xst;
        const float* hin = (t == 0) ? h0  : hst;

        k_attn2<<<256, 1024, 0, stream>>>(EW, enc, qpre, ba, vvec, ctxb);

        k_bcd<<<64, 512, 0, stream>>>(xin, hin, ctxb, Wa,
                                      W_ih, b_ih, W_hh, b_hh, WoT, bo,
                                      qpre, hst, xst, out, t);
    }
}

// Round 8
// 11281.406 us; speedup vs baseline: 2.3889x; 1.1194x over previous
//
#include <hip/hip_runtime.h>
#include <math.h>

// Problem constants
#define SS 256
#define BB 256
#define HH 512
#define OO 64
#define NSTEP 63

// ---------------------------------------------------------------------------
// K0: EW = enc @ Wa_bot (M=65536,K=512,N=512) fp32, 128x128 tile.
// Output relayout: row m = s*256+b -> EW[b][s][h] (contiguous per batch).
// ---------------------------------------------------------------------------
__global__ __launch_bounds__(256) void k_ew_gemm(const float* __restrict__ A,
                                                 const float* __restrict__ Bm,
                                                 float* __restrict__ C)
{
    __shared__ float As[8][132];
    __shared__ float Bs[8][132];
    const int tid = threadIdx.x;
    const int bm = blockIdx.x * 128;
    const int bn = blockIdx.y * 128;
    const int tx = tid & 15;
    const int ty = tid >> 4;
    const int a_row = tid >> 1;
    const int a_k4 = (tid & 1) * 4;
    const int b_row = tid >> 5;
    const int b_n4 = (tid & 31) * 4;

    float acc[8][8];
#pragma unroll
    for (int i = 0; i < 8; i++)
#pragma unroll
        for (int j = 0; j < 8; j++) acc[i][j] = 0.f;

    for (int kt = 0; kt < 512; kt += 8) {
        float4 av = *(const float4*)(A + (size_t)(bm + a_row) * 512 + kt + a_k4);
        As[a_k4 + 0][a_row] = av.x;
        As[a_k4 + 1][a_row] = av.y;
        As[a_k4 + 2][a_row] = av.z;
        As[a_k4 + 3][a_row] = av.w;
        *(float4*)(&Bs[b_row][b_n4]) = *(const float4*)(Bm + (size_t)(kt + b_row) * 512 + bn + b_n4);
        __syncthreads();
#pragma unroll
        for (int kk = 0; kk < 8; kk++) {
            float av8[8], bv8[8];
            *(float4*)&av8[0] = *(const float4*)&As[kk][ty * 4];
            *(float4*)&av8[4] = *(const float4*)&As[kk][64 + ty * 4];
            *(float4*)&bv8[0] = *(const float4*)&Bs[kk][tx * 4];
            *(float4*)&bv8[4] = *(const float4*)&Bs[kk][64 + tx * 4];
#pragma unroll
            for (int i = 0; i < 8; i++)
#pragma unroll
                for (int j = 0; j < 8; j++) acc[i][j] += av8[i] * bv8[j];
        }
        __syncthreads();
    }
#pragma unroll
    for (int i = 0; i < 8; i++) {
        int m = bm + ((i < 4) ? (ty * 4 + i) : (64 + ty * 4 + i - 4));
        size_t mrow = (size_t)((m & 255) * 256 + (m >> 8));
        float4 o0 = make_float4(acc[i][0], acc[i][1], acc[i][2], acc[i][3]);
        float4 o1 = make_float4(acc[i][4], acc[i][5], acc[i][6], acc[i][7]);
        *(float4*)(C + mrow * 512 + bn + tx * 4) = o0;
        *(float4*)(C + mrow * 512 + bn + 64 + tx * 4) = o1;
    }
}

// ---------------------------------------------------------------------------
// q init: qc = h0 @ Wa_top  (fp32; ba added in attention)
// ---------------------------------------------------------------------------
__global__ __launch_bounds__(256) void k_qinit(const float* __restrict__ A,
                                               const float* __restrict__ Wa,
                                               float* __restrict__ qc)
{
    __shared__ float As[32][33];
    __shared__ float Bs[32][33];
    const int tid = threadIdx.x;
    const int bn = blockIdx.x * 32;
    const int bm = blockIdx.y * 32;
    const int tx = tid & 15;
    const int ty = tid >> 4;
    const int l_row = tid >> 3;
    const int l_c4 = (tid & 7) * 4;

    float acc00 = 0.f, acc01 = 0.f, acc10 = 0.f, acc11 = 0.f;
    for (int kt = 0; kt < 512; kt += 32) {
#pragma unroll
        for (int i = 0; i < 4; i++)
            As[l_c4 + i][l_row] = A[(size_t)(bm + l_row) * 512 + kt + l_c4 + i];
#pragma unroll
        for (int i = 0; i < 4; i++)
            Bs[l_row][l_c4 + i] = Wa[(size_t)(kt + l_row) * 512 + bn + l_c4 + i];
        __syncthreads();
#pragma unroll
        for (int kk = 0; kk < 32; kk++) {
            float a0 = As[kk][ty * 2], a1 = As[kk][ty * 2 + 1];
            float b0 = Bs[kk][tx * 2], b1 = Bs[kk][tx * 2 + 1];
            acc00 += a0 * b0; acc01 += a0 * b1;
            acc10 += a1 * b0; acc11 += a1 * b1;
        }
        __syncthreads();
    }
    qc[(size_t)(bm + ty * 2) * 512 + bn + tx * 2]     = acc00;
    qc[(size_t)(bm + ty * 2) * 512 + bn + tx * 2 + 1] = acc01;
    qc[(size_t)(bm + ty * 2 + 1) * 512 + bn + tx * 2]     = acc10;
    qc[(size_t)(bm + ty * 2 + 1) * 512 + bn + tx * 2 + 1] = acc11;
}

// ---------------------------------------------------------------------------
// k_attn: block = batch b, 512 threads. fp32.
// Reads q from qc[b], writes ctx into the SAME buffer qc[b] (block-local
// alias: all reads happen before the write, separated by __syncthreads).
// ---------------------------------------------------------------------------
__global__ __launch_bounds__(512) void k_attn(const float* __restrict__ EW,
                                              const float* __restrict__ enc,
                                              const float* __restrict__ ba,
                                              const float* __restrict__ vvec,
                                              float* __restrict__ qc)
{
    __shared__ float qs[512], vs[512], sc[256], red[16];
    const int b = blockIdx.x;
    const int tid = threadIdx.x;

    qs[tid] = qc[b * 512 + tid] + ba[tid];
    vs[tid] = vvec[tid];
    __syncthreads();

    const int w = tid >> 6;
    const int l = tid & 63;
    const float* qp0 = qs + l * 4;
    const float* vp0 = vs + l * 4;
    const float* qp1 = qs + 256 + l * 4;
    const float* vp1 = vs + 256 + l * 4;

    for (int i = 0; i < 32; i++) {
        int s = w * 32 + i;
        const float4* p4 = (const float4*)(EW + ((size_t)(b * 256 + s)) * 512);
        float4 e0 = p4[l];
        float4 e1 = p4[l + 64];
        float a;
        a  = vp0[0] * tanhf(e0.x + qp0[0]);
        a += vp0[1] * tanhf(e0.y + qp0[1]);
        a += vp0[2] * tanhf(e0.z + qp0[2]);
        a += vp0[3] * tanhf(e0.w + qp0[3]);
        a += vp1[0] * tanhf(e1.x + qp1[0]);
        a += vp1[1] * tanhf(e1.y + qp1[1]);
        a += vp1[2] * tanhf(e1.z + qp1[2]);
        a += vp1[3] * tanhf(e1.w + qp1[3]);
#pragma unroll
        for (int off = 32; off; off >>= 1) a += __shfl_down(a, off);
        if (l == 0) sc[s] = a;
    }
    __syncthreads();

    if (tid < 256) {
        float m = sc[tid];
#pragma unroll
        for (int off = 32; off; off >>= 1) m = fmaxf(m, __shfl_down(m, off));
        if ((tid & 63) == 0) red[tid >> 6] = m;
    }
    __syncthreads();
    if (tid < 256) {
        float mx = fmaxf(fmaxf(red[0], red[1]), fmaxf(red[2], red[3]));
        float e = expf(sc[tid] - mx);
        sc[tid] = e;
        float ssum = e;
#pragma unroll
        for (int off = 32; off; off >>= 1) ssum += __shfl_down(ssum, off);
        if ((tid & 63) == 0) red[8 + (tid >> 6)] = ssum;
    }
    __syncthreads();
    const float inv = 1.0f / (red[8] + red[9] + red[10] + red[11]);

    // context: h = tid; enc is [s][b][h] (strided 2KB-chunk reads)
    const int h = tid;
    const float* ep = enc + b * 512 + h;
    float acc = 0.f;
#pragma unroll 4
    for (int s = 0; s < 256; s++) {
        acc += sc[s] * ep[(size_t)s * (256 * 512)];
    }
    qc[b * 512 + h] = acc * inv;   // ctx overwrites q (alias)
}

// ---------------------------------------------------------------------------
// k_h: h_new = tanh([x|ctx|h_prev] @ [W_ih|W_hh]^T + b_ih + b_hh)
// M=256,N=512,K=1088. Tile 16m x 64n, BK=32, 256 thr, 1m x 4n/thread.
// grid (8 n-tiles, 16 m-tiles) = 128 blocks.
// hin and hout are SEPARATE buffers (double-buffered by caller) — n-tiling
// splits rows across blocks, so in-place update would race (R7 bug).
// ---------------------------------------------------------------------------
__global__ __launch_bounds__(256) void k_h(
    const float* __restrict__ xin, const float* __restrict__ ctx,
    const float* __restrict__ hin,
    const float* __restrict__ W_ih, const float* __restrict__ W_hh,
    const float* __restrict__ b_ih, const float* __restrict__ b_hh,
    float* __restrict__ hout)
{
    __shared__ float As[32][17];
    __shared__ float Bs[32][72];
    const int tid = threadIdx.x;
    const int bn = blockIdx.x * 64;
    const int bm = blockIdx.y * 16;
    const int sa_m = tid >> 4;
    const int sa_k2 = (tid & 15) * 2;
    const int sb_n = tid & 63;
    const int sb_k8 = (tid >> 6) * 8;
    const int cm = tid >> 4;
    const int cn4 = (tid & 15) * 4;

    float acc0 = 0.f, acc1 = 0.f, acc2 = 0.f, acc3 = 0.f;

    for (int kt = 0; kt < 1088; kt += 32) {
        // ---- stage A (16m x 32k); k-tile never straddles sources ----
        {
            const int m = bm + sa_m;
            float2 f;
            if (kt < 64) {
                f = *(const float2*)(xin + (size_t)m * 64 + kt + sa_k2);
            } else if (kt < 576) {
                f = *(const float2*)(ctx + (size_t)m * 512 + (kt - 64) + sa_k2);
            } else {
                f = *(const float2*)(hin + (size_t)m * 512 + (kt - 576) + sa_k2);
            }
            As[sa_k2 + 0][sa_m] = f.x;
            As[sa_k2 + 1][sa_m] = f.y;
        }
        // ---- stage B (32k x 64n) transposed from W[n][k] rows ----
        {
            const int n = bn + sb_n;
            const float* wr = (kt < 576) ? (W_ih + (size_t)n * 576 + kt)
                                         : (W_hh + (size_t)n * 512 + (kt - 576));
            float4 f0 = *(const float4*)(wr + sb_k8);
            float4 f1 = *(const float4*)(wr + sb_k8 + 4);
            Bs[sb_k8 + 0][sb_n] = f0.x; Bs[sb_k8 + 1][sb_n] = f0.y;
            Bs[sb_k8 + 2][sb_n] = f0.z; Bs[sb_k8 + 3][sb_n] = f0.w;
            Bs[sb_k8 + 4][sb_n] = f1.x; Bs[sb_k8 + 5][sb_n] = f1.y;
            Bs[sb_k8 + 6][sb_n] = f1.z; Bs[sb_k8 + 7][sb_n] = f1.w;
        }
        __syncthreads();
#pragma unroll
        for (int kk = 0; kk < 32; kk++) {
            float a = As[kk][cm];
            float4 b4 = *(const float4*)&Bs[kk][cn4];
            acc0 += a * b4.x; acc1 += a * b4.y;
            acc2 += a * b4.z; acc3 += a * b4.w;
        }
        __syncthreads();
    }
    const int m = bm + cm;
    const int n0 = bn + cn4;
    float4 hv;
    hv.x = tanhf(acc0 + b_ih[n0 + 0] + b_hh[n0 + 0]);
    hv.y = tanhf(acc1 + b_ih[n0 + 1] + b_hh[n0 + 1]);
    hv.z = tanhf(acc2 + b_ih[n0 + 2] + b_hh[n0 + 2]);
    hv.w = tanhf(acc3 + b_ih[n0 + 3] + b_hh[n0 + 3]);
    *(float4*)(hout + (size_t)m * 512 + n0) = hv;
}

// ---------------------------------------------------------------------------
// k_oq: N=576 GEMM on h_new: n<512: qc = h @ Wa_top (pre-bias q);
// n in [512,576): out = h @ Wo^T + bo -> dout + fused argmax -> xst.
// Tile 16m x 64n, BK=32, grid (9 n-tiles, 16 m-tiles) = 144 blocks.
// ---------------------------------------------------------------------------
__global__ __launch_bounds__(256) void k_oq(
    const float* __restrict__ hst,
    const float* __restrict__ Wa, const float* __restrict__ Wo,
    const float* __restrict__ bo,
    float* __restrict__ qc,
    float* __restrict__ dout, int t,
    float* __restrict__ xst)
{
    __shared__ float As[32][17];
    __shared__ float Bs[32][72];
    const int tid = threadIdx.x;
    const int bn = blockIdx.x * 64;       // 0..576
    const int bm = blockIdx.y * 16;
    const bool is_out = (bn >= 512);
    const int sa_m = tid >> 4;
    const int sa_k2 = (tid & 15) * 2;
    const int sb_n = tid & 63;
    const int sb_k8 = (tid >> 6) * 8;
    const int wa_k = tid >> 3;
    const int wa_n8 = (tid & 7) * 8;
    const int cm = tid >> 4;
    const int cn4 = (tid & 15) * 4;

    float acc0 = 0.f, acc1 = 0.f, acc2 = 0.f, acc3 = 0.f;

    for (int kt = 0; kt < 512; kt += 32) {
        {
            float2 f = *(const float2*)(hst + (size_t)(bm + sa_m) * 512 + kt + sa_k2);
            As[sa_k2 + 0][sa_m] = f.x;
            As[sa_k2 + 1][sa_m] = f.y;
        }
        if (!is_out) {
            const float* wr = Wa + (size_t)(kt + wa_k) * 512 + bn + wa_n8;
            *(float4*)&Bs[wa_k][wa_n8]     = *(const float4*)(wr);
            *(float4*)&Bs[wa_k][wa_n8 + 4] = *(const float4*)(wr + 4);
        } else {
            const float* wr = Wo + (size_t)sb_n * 512 + kt;
            float4 f0 = *(const float4*)(wr + sb_k8);
            float4 f1 = *(const float4*)(wr + sb_k8 + 4);
            Bs[sb_k8 + 0][sb_n] = f0.x; Bs[sb_k8 + 1][sb_n] = f0.y;
            Bs[sb_k8 + 2][sb_n] = f0.z; Bs[sb_k8 + 3][sb_n] = f0.w;
            Bs[sb_k8 + 4][sb_n] = f1.x; Bs[sb_k8 + 5][sb_n] = f1.y;
            Bs[sb_k8 + 6][sb_n] = f1.z; Bs[sb_k8 + 7][sb_n] = f1.w;
        }
        __syncthreads();
#pragma unroll
        for (int kk = 0; kk < 32; kk++) {
            float a = As[kk][cm];
            float4 b4 = *(const float4*)&Bs[kk][cn4];
            acc0 += a * b4.x; acc1 += a * b4.y;
            acc2 += a * b4.z; acc3 += a * b4.w;
        }
        __syncthreads();
    }

    const int m = bm + cm;
    if (!is_out) {
        float4 qv = make_float4(acc0, acc1, acc2, acc3);
        *(float4*)(qc + (size_t)m * 512 + bn + cn4) = qv;
    } else {
        float* outs = &Bs[0][0];   // reuse as [16][64] scratch
        float v0 = acc0 + bo[cn4 + 0];
        float v1 = acc1 + bo[cn4 + 1];
        float v2 = acc2 + bo[cn4 + 2];
        float v3 = acc3 + bo[cn4 + 3];
        float* dp = dout + (size_t)m * (OO * NSTEP) + (size_t)cn4 * NSTEP + t;
        dp[0 * NSTEP] = v0; dp[1 * NSTEP] = v1;
        dp[2 * NSTEP] = v2; dp[3 * NSTEP] = v3;
        outs[cm * 64 + cn4 + 0] = v0;
        outs[cm * 64 + cn4 + 1] = v1;
        outs[cm * 64 + cn4 + 2] = v2;
        outs[cm * 64 + cn4 + 3] = v3;
        __syncthreads();
        if (tid < 16) {
            const int ml = tid;
            float bv = outs[ml * 64];
            int bi = 0;
            for (int j = 1; j < 64; j++) {
                float v = outs[ml * 64 + j];
                if (v > bv) { bv = v; bi = j; }   // first-index tie-break
            }
            float* xr = xst + (size_t)(bm + ml) * 64;
            for (int j = 0; j < 64; j++) xr[j] = (j == bi) ? 1.0f : 0.0f;
        }
    }
}

// ---------------------------------------------------------------------------
extern "C" void kernel_launch(void* const* d_in, const int* in_sizes, int n_in,
                              void* d_out, int out_size, void* d_ws, size_t ws_size,
                              hipStream_t stream)
{
    const float* sos  = (const float*)d_in[0];
    const float* h0   = (const float*)d_in[1];
    const float* enc  = (const float*)d_in[2];
    const float* Wa   = (const float*)d_in[3];
    const float* ba   = (const float*)d_in[4];
    const float* vvec = (const float*)d_in[5];
    const float* W_ih = (const float*)d_in[6];
    const float* b_ih = (const float*)d_in[7];
    const float* W_hh = (const float*)d_in[8];
    const float* b_hh = (const float*)d_in[9];
    const float* Wo   = (const float*)d_in[10];
    const float* bo   = (const float*)d_in[11];
    float* out = (float*)d_out;

    // Workspace: 33,964,032 floats (135.9 MB) <= verified budget 34,111,488.
    float* ws = (float*)d_ws;
    float* EW  = ws; ws += (size_t)SS * BB * HH;   // 33,554,432  [b][s][h]
    float* qc  = ws; ws += BB * HH;                // q / ctx (aliased)
    float* hb0 = ws; ws += BB * HH;                // h double buffer A
    float* hb1 = ws; ws += BB * HH;                // h double buffer B
    float* xst = ws; ws += BB * OO;                // one-hot

    // ---- Precompute ----
    k_ew_gemm<<<dim3(512, 4), 256, 0, stream>>>(enc, Wa + 512 * 512, EW);
    k_qinit<<<dim3(16, 8), 256, 0, stream>>>(h0, Wa, qc);

    // ---- 63 decode steps: 3 kernels per step ----
    for (int t = 0; t < NSTEP; t++) {
        const float* xin  = (t == 0) ? sos : xst;
        const float* hin  = (t == 0) ? h0 : ((t & 1) ? hb0 : hb1);
        float*       hout = (t & 1) ? hb1 : hb0;

        // scores+softmax+context (ctx overwrites q in qc)
        k_attn<<<256, 512, 0, stream>>>(EW, enc, ba, vvec, qc);

        // h_new (double-buffered: hin != hout)
        k_h<<<dim3(8, 16), 256, 0, stream>>>(xin, qc, hin,
                                             W_ih, W_hh, b_ih, b_hh, hout);

        // q_next (into qc) + out/dout/argmax/one-hot
        k_oq<<<dim3(9, 16), 256, 0, stream>>>(hout, Wa, Wo, bo,
                                              qc, out, t, xst);
    }
}